// Round 5
// baseline (331.461 us; speedup 1.0000x reference)
//
#include <hip/hip_runtime.h>
#include <math.h>

#define POUT 7
#define NCH 256

// ---------------- level geometry (elements) ----------------
#define HW0 40000
#define HW1 10000
#define HW2 2500
#define HW3 625
#define WS_OFF0 0
#define WS_OFF1 (2*NCH*HW0)
#define WS_OFF2 (WS_OFF1 + 2*NCH*HW1)
#define WS_OFF3 (WS_OFF2 + 2*NCH*HW2)
#define WS_ELEMS (WS_OFF3 + 2*NCH*HW3)      // 27,200,000 floats = 108.8 MB

#define MAXSPAN 208                          // >= max map dim (200) + pad
#define CHUNK   16                           // rows per work item
#define SLOTS   13                           // ceil(200/16) chunk slots per box

// ---------------- NCHW -> NHWC tiled transpose ----------------
__global__ __launch_bounds__(256) void transpose_cl_kernel(
    const float* __restrict__ in, float* __restrict__ out, int HW)
{
    __shared__ float tile[32][33];
    const int p0 = blockIdx.x * 32;
    const int c0 = blockIdx.y * 32;
    const int b  = blockIdx.z;
    const int tx = threadIdx.x, ty = threadIdx.y;

    const float* src = in + ((size_t)b * NCH + c0) * (size_t)HW + p0;
    #pragma unroll
    for (int j = 0; j < 32; j += 8) {
        const int c = ty + j;
        if (p0 + tx < HW) tile[c][tx] = src[(size_t)c * HW + tx];
    }
    __syncthreads();
    float* dst = out + ((size_t)b * HW + p0) * NCH + c0;
    #pragma unroll
    for (int j = 0; j < 32; j += 8) {
        const int p = ty + j;
        if (p0 + p < HW) dst[(size_t)p * NCH + tx] = tile[tx][p];
    }
}

// ---------------- chunked separable RoIAlign from NHWC ----------------
// Item = (box, 16-row y-chunk). Block 256 thr, thread t = channel.
// Single-chunk boxes: plain coalesced stores. Multi-chunk: unsafeAtomicAdd
// into zeroed out. Inner loop: x-tile of 4 with Wx in registers (transposed
// LDS layout, zero-padded edge), y inner with next-row prefetch; only Wy is
// read from LDS per y (2x ds_read_b128 per 4 positions).
__global__ __launch_bounds__(256, 4) void roi_chunk_kernel(
    const float* __restrict__ ws, const float* __restrict__ props,
    float* __restrict__ out, int boxes_per_img)
{
    // smem: [ Wy: 208*8 = 1664 floats | WxT: 7*208 = 1456 floats ] = 3120
    // reused after compute as 64x49 store stage (3136 floats)
    __shared__ float smem[3136];
    float* sWy  = smem;                 // [y][8] (p<7 used)
    float* sWxT = smem + MAXSPAN * 8;   // [q][208], 0.25 folded, zero-padded

    const int bx    = blockIdx.x;
    const int n     = bx / SLOTS;
    const int chunk = bx - n * SLOTS;
    const int t     = threadIdx.x;
    const int b     = n / boxes_per_img;

    const float4 box = ((const float4*)props)[n];
    const float area = (box.z - box.x) * (box.w - box.y);
    float lvlf = floorf(4.0f + log2f(sqrtf(area) / 224.0f + 1e-6f));
    lvlf = fminf(fmaxf(lvlf, 2.0f), 5.0f) - 2.0f;
    const int l = (int)lvlf;

    int sz; size_t lvl_off;
    if      (l == 0) { sz = 200; lvl_off = WS_OFF0; }
    else if (l == 1) { sz = 100; lvl_off = WS_OFF1; }
    else if (l == 2) { sz = 50;  lvl_off = WS_OFF2; }
    else             { sz = 25;  lvl_off = WS_OFF3; }
    const int HW = sz * sz;
    const float scale = 0.25f / (float)(1 << l);

    const float x0s = box.x * scale, y0s = box.y * scale;
    const float x1s = box.z * scale, y1s = box.w * scale;
    const float bin_w = fmaxf(x1s - x0s, 1.0f) / (float)POUT;
    const float bin_h = fmaxf(y1s - y0s, 1.0f) / (float)POUT;

    auto lo_of = [sz](float coord) -> int {
        float cc = fmaxf(coord, 0.0f);
        int lo0 = (int)floorf(cc);
        return (lo0 >= sz - 1) ? sz - 1 : lo0;
    };
    auto hi_of = [sz](float coord) -> int {
        float cc = fmaxf(coord, 0.0f);
        int lo0 = (int)floorf(cc);
        return (lo0 >= sz - 1) ? sz - 1 : lo0 + 1;
    };
    const int ymin = lo_of(y0s + 0.25f * bin_h);
    const int ymax = hi_of(y0s + 6.75f * bin_h);
    const int xmin = lo_of(x0s + 0.25f * bin_w);
    const int xmax = hi_of(x0s + 6.75f * bin_w);
    const int R  = ymax - ymin + 1;          // <= 200
    const int Cl = xmax - xmin + 1;

    const int nch = (R + CHUNK - 1) / CHUNK;
    if (chunk >= nch) return;                // uniform early-exit, pre-barrier
    const int r0 = chunk * CHUNK;
    const int r1 = (r0 + CHUNK < R) ? r0 + CHUNK : R;

    // zero whole weight region (simple, 13 iters)
    for (int i = t; i < 3120; i += 256) smem[i] = 0.0f;
    __syncthreads();

    if (t < 7) {                             // build Wy rows (full R)
        #pragma unroll
        for (int iy = 0; iy < 2; ++iy) {
            const float yc = y0s + ((float)t + ((float)iy + 0.5f) * 0.5f) * bin_h;
            const bool  v  = (yc >= -1.0f) && (yc <= (float)sz);
            const float cc = fmaxf(yc, 0.0f);
            const int lo0  = (int)floorf(cc);
            const bool edge = lo0 >= sz - 1;
            const int lo = edge ? sz - 1 : lo0;
            const int hi = edge ? sz - 1 : lo0 + 1;
            const float fr = edge ? 0.0f : cc - (float)lo0;
            const float m  = v ? 1.0f : 0.0f;
            sWy[(lo - ymin) * 8 + t] += (1.0f - fr) * m;
            sWy[(hi - ymin) * 8 + t] += fr * m;
        }
    } else if (t >= 64 && t < 71) {          // build WxT rows
        const int q = t - 64;
        #pragma unroll
        for (int ix = 0; ix < 2; ++ix) {
            const float xc = x0s + ((float)q + ((float)ix + 0.5f) * 0.5f) * bin_w;
            const bool  v  = (xc >= -1.0f) && (xc <= (float)sz);
            const float cc = fmaxf(xc, 0.0f);
            const int lo0  = (int)floorf(cc);
            const bool edge = lo0 >= sz - 1;
            const int lo = edge ? sz - 1 : lo0;
            const int hi = edge ? sz - 1 : lo0 + 1;
            const float fr = edge ? 0.0f : cc - (float)lo0;
            const float m  = v ? 0.25f : 0.0f;   // fold subsample mean
            sWxT[q * MAXSPAN + (lo - xmin)] += (1.0f - fr) * m;
            sWxT[q * MAXSPAN + (hi - xmin)] += fr * m;
        }
    }
    __syncthreads();

    const int c = t;
    const float* fb = ws + lvl_off + (size_t)b * (size_t)HW * NCH + c;
    const size_t rowstride = (size_t)sz * NCH;

    float acc[49];
    #pragma unroll
    for (int i = 0; i < 49; ++i) acc[i] = 0.0f;

    for (int xt = 0; xt < Cl; xt += 4) {
        // Wx tile -> registers (transposed layout: one float4 per q).
        // Columns beyond Cl have zero weight (padded LDS), loads clamp.
        float4 wq[7];
        #pragma unroll
        for (int q = 0; q < 7; ++q)
            wq[q] = *(const float4*)&sWxT[q * MAXSPAN + xt];

        int offk[4];
        #pragma unroll
        for (int k = 0; k < 4; ++k) {
            int col = xt + k;
            col = (col < Cl) ? col : Cl - 1;
            offk[k] = (xmin + col) * NCH;
        }

        const float* rowp = fb + (size_t)(ymin + r0) * rowstride;
        float v0 = rowp[offk[0]], v1 = rowp[offk[1]];
        float v2 = rowp[offk[2]], v3 = rowp[offk[3]];

        for (int y = r0; y < r1; ++y) {
            const float c0 = v0, c1 = v1, c2 = v2, c3 = v3;
            const float* nrow = rowp + rowstride;
            if (y + 1 < r1) {                 // prefetch next row
                v0 = nrow[offk[0]]; v1 = nrow[offk[1]];
                v2 = nrow[offk[2]]; v3 = nrow[offk[3]];
            }
            rowp = nrow;

            float wy[8];
            *(float4*)&wy[0] = *(const float4*)&sWy[y * 8 + 0];
            *(float4*)&wy[4] = *(const float4*)&sWy[y * 8 + 4];

            float tq[7];
            #pragma unroll
            for (int q = 0; q < 7; ++q)
                tq[q] = wq[q].x * c0 + wq[q].y * c1 + wq[q].z * c2 + wq[q].w * c3;

            #pragma unroll
            for (int p = 0; p < 7; ++p)
                #pragma unroll
                for (int q = 0; q < 7; ++q)
                    acc[p * 7 + q] += wy[p] * tq[q];
        }
    }

    // ---- epilogue: stage 64ch x 49 per round, coalesced store/atomic ----
    __syncthreads();                          // weights dead; smem = stage
    const bool use_atomic = (nch > 1);
    float* obase = out + (size_t)n * (NCH * 49);
    #pragma unroll
    for (int r = 0; r < 4; ++r) {
        if ((t >> 6) == r) {
            #pragma unroll
            for (int i = 0; i < 49; ++i) smem[(t & 63) * 49 + i] = acc[i];
        }
        __syncthreads();
        float* dst = obase + r * (64 * 49);
        if (use_atomic) {
            for (int i = t; i < 64 * 49; i += 256)
                unsafeAtomicAdd(&dst[i], smem[i]);
        } else {
            float4* d4 = (float4*)dst;
            const float4* s4 = (const float4*)smem;
            for (int i = t; i < 64 * 49 / 4; i += 256) d4[i] = s4[i];
        }
        __syncthreads();
    }
}

// ---------------- fallback (round-1 NCHW kernel) ----------------
__global__ __launch_bounds__(256, 4) void roi_align_nchw_kernel(
    const float* __restrict__ f0, const float* __restrict__ f1,
    const float* __restrict__ f2, const float* __restrict__ f3,
    const float* __restrict__ props, float* __restrict__ out, int boxes_per_img)
{
    const int n = blockIdx.x;
    const int t = threadIdx.x;
    if (t >= 196) return;
    const int bin = t >> 2, q = t & 3;
    const int ph = bin / POUT, pw = bin % POUT;
    const int iy = q >> 1,    ix = q & 1;
    const int b = n / boxes_per_img;

    const float4 box = ((const float4*)props)[n];
    const float area = (box.z - box.x) * (box.w - box.y);
    float lvlf = floorf(4.0f + log2f(sqrtf(area) / 224.0f + 1e-6f));
    lvlf = fminf(fmaxf(lvlf, 2.0f), 5.0f) - 2.0f;
    const int l = (int)lvlf;

    const float* feat; int sz;
    if      (l == 0) { feat = f0; sz = 200; }
    else if (l == 1) { feat = f1; sz = 100; }
    else if (l == 2) { feat = f2; sz = 50;  }
    else             { feat = f3; sz = 25;  }
    const float scale = 0.25f / (float)(1 << l);

    const float x0 = box.x * scale, y0 = box.y * scale;
    const float x1 = box.z * scale, y1 = box.w * scale;
    const float bin_w = fmaxf(x1 - x0, 1.0f) / (float)POUT;
    const float bin_h = fmaxf(y1 - y0, 1.0f) / (float)POUT;
    const float ysamp = y0 + ((float)ph + ((float)iy + 0.5f) * 0.5f) * bin_h;
    const float xsamp = x0 + ((float)pw + ((float)ix + 0.5f) * 0.5f) * bin_w;

    const bool  vy  = (ysamp >= -1.0f) && (ysamp <= (float)sz);
    const float cy  = fmaxf(ysamp, 0.0f);
    const int   yl0 = (int)floorf(cy);
    const bool  ey  = yl0 >= sz - 1;
    const int   yl  = ey ? sz - 1 : yl0;
    const int   yh  = ey ? sz - 1 : yl0 + 1;
    const float ly  = ey ? 0.0f : cy - (float)yl0;
    const bool  vx  = (xsamp >= -1.0f) && (xsamp <= (float)sz);
    const float cx  = fmaxf(xsamp, 0.0f);
    const int   xl0 = (int)floorf(cx);
    const bool  ex  = xl0 >= sz - 1;
    const int   xl  = ex ? sz - 1 : xl0;
    const int   xh  = ex ? sz - 1 : xl0 + 1;
    const float lx  = ex ? 0.0f : cx - (float)xl0;

    const float hy = 1.0f - ly, hx = 1.0f - lx;
    const float m  = (vy && vx) ? 1.0f : 0.0f;
    const float w00 = hy * hx * m, w01 = hy * lx * m;
    const float w10 = ly * hx * m, w11 = ly * lx * m;

    const int HW = sz * sz;
    const float* base = feat + (size_t)b * NCH * HW;
    int o00 = yl * sz + xl, o01 = yl * sz + xh;
    int o10 = yh * sz + xl, o11 = yh * sz + xh;
    float* op = out + (size_t)n * NCH * (POUT * POUT) + bin;

    #pragma unroll 4
    for (int cch = 0; cch < NCH; ++cch) {
        float v = w00 * base[o00] + w01 * base[o01]
                + w10 * base[o10] + w11 * base[o11];
        v += __shfl_xor(v, 1);
        v += __shfl_xor(v, 2);
        if (q == 0) op[cch * (POUT * POUT)] = v * 0.25f;
        o00 += HW; o01 += HW; o10 += HW; o11 += HW;
    }
}

extern "C" void kernel_launch(void* const* d_in, const int* in_sizes, int n_in,
                              void* d_out, int out_size, void* d_ws, size_t ws_size,
                              hipStream_t stream) {
    const float* f0 = (const float*)d_in[0];
    const float* f1 = (const float*)d_in[1];
    const float* f2 = (const float*)d_in[2];
    const float* f3 = (const float*)d_in[3];
    const float* props = (const float*)d_in[4];
    float* out = (float*)d_out;

    const int N = in_sizes[4] / 4;                 // 1024 boxes
    const int B = in_sizes[0] / (NCH * HW0);       // 2 images
    const int boxes_per_img = N / B;               // 512

    if (ws_size >= (size_t)WS_ELEMS * sizeof(float)) {
        float* wsf = (float*)d_ws;
        // zero output (multi-chunk boxes accumulate atomically)
        hipMemsetAsync(out, 0, (size_t)out_size * sizeof(float), stream);
        dim3 blk(32, 8, 1);
        transpose_cl_kernel<<<dim3((HW0 + 31) / 32, 8, B), blk, 0, stream>>>(f0, wsf + WS_OFF0, HW0);
        transpose_cl_kernel<<<dim3((HW1 + 31) / 32, 8, B), blk, 0, stream>>>(f1, wsf + WS_OFF1, HW1);
        transpose_cl_kernel<<<dim3((HW2 + 31) / 32, 8, B), blk, 0, stream>>>(f2, wsf + WS_OFF2, HW2);
        transpose_cl_kernel<<<dim3((HW3 + 31) / 32, 8, B), blk, 0, stream>>>(f3, wsf + WS_OFF3, HW3);
        roi_chunk_kernel<<<N * SLOTS, 256, 0, stream>>>(wsf, props, out, boxes_per_img);
    } else {
        roi_align_nchw_kernel<<<N, 256, 0, stream>>>(f0, f1, f2, f3, props, out, boxes_per_img);
    }
}

// Round 6
// 241.071 us; speedup vs baseline: 1.3750x; 1.3750x over previous
//
#include <hip/hip_runtime.h>
#include <hip/hip_fp16.h>
#include <math.h>

#define POUT 7
#define NCH 256

// ---------------- level geometry (elements) ----------------
#define HW0 40000
#define HW1 10000
#define HW2 2500
#define HW3 625
#define WS_OFF0 0
#define WS_OFF1 (2*NCH*HW0)
#define WS_OFF2 (WS_OFF1 + 2*NCH*HW1)
#define WS_OFF3 (WS_OFF2 + 2*NCH*HW2)
#define WS_ELEMS (WS_OFF3 + 2*NCH*HW3)      // 27,200,000 floats = 108.8 MB
// +256 floats slack: o01/o11 = o00/o10 + 256 may read 1 element-row past the
// last image (weight is exactly 0 there; value irrelevant, must be mapped).
#define WS_NEED  ((size_t)(WS_ELEMS + 256) * sizeof(float))

// ---------------- NCHW -> NHWC transpose, 64x64 tiles, float4 both sides ----
__global__ __launch_bounds__(256) void transpose_cl_kernel(
    const float* __restrict__ in, float* __restrict__ out, int HW)
{
    __shared__ float tile[64][65];
    const int p0 = blockIdx.x * 64;
    const int c0 = blockIdx.y * 64;
    const int b  = blockIdx.z;
    const int tx = threadIdx.x & 15;       // 16 lanes x float4 = 64 positions
    const int ty = threadIdx.x >> 4;       // 16 rows x 4 = 64 channels

    const float* src = in + ((size_t)b * NCH + c0) * (size_t)HW + p0;
    const bool full = (p0 + 64 <= HW);
    #pragma unroll
    for (int j = 0; j < 4; ++j) {
        const int c = ty * 4 + j;
        const int p = tx * 4;
        if (full) {
            const float4 v = *(const float4*)&src[(size_t)c * HW + p];
            *(float4*)&tile[c][p] = v;
        } else {
            #pragma unroll
            for (int k = 0; k < 4; ++k)
                if (p0 + p + k < HW) tile[c][p + k] = src[(size_t)c * HW + p + k];
        }
    }
    __syncthreads();
    float* dst = out + ((size_t)b * HW + p0) * NCH + c0;
    #pragma unroll
    for (int j = 0; j < 4; ++j) {
        const int p = ty * 4 + j;
        if (p0 + p < HW) {
            float4 w;
            w.x = tile[tx * 4 + 0][p];
            w.y = tile[tx * 4 + 1][p];
            w.z = tile[tx * 4 + 2][p];
            w.w = tile[tx * 4 + 3][p];
            *(float4*)&dst[(size_t)p * NCH + tx * 4] = w;
        }
    }
}

// ---------------- uniform 196-sample gather from NHWC ----------------
// One block per box (grid 1024 = exactly 4 blocks/CU, all identical cost:
// zero tail imbalance). Thread t = channel. Phase A: threads 0..195 pack one
// int4 record per sample: {o00, half2(w00,w01), half2(w10,w11), o10};
// o01/o11 derived as +256 immediate offsets. Phase B: fully unrolled 49 bins
// x 4 samples: 1 ds_read_b128 + 4 coalesced loads + 4 FMA per sample.
__global__ __launch_bounds__(256, 4) void roi_gather_kernel(
    const float* __restrict__ ws, const float* __restrict__ props,
    float* __restrict__ out, int boxes_per_img)
{
    __shared__ int4  sRec[196];
    __shared__ float sStage[64 * 49];

    const int n = blockIdx.x;
    const int t = threadIdx.x;
    const int b = n / boxes_per_img;

    const float4 box = ((const float4*)props)[n];
    const float area = (box.z - box.x) * (box.w - box.y);
    float lvlf = floorf(4.0f + log2f(sqrtf(area) / 224.0f + 1e-6f));
    lvlf = fminf(fmaxf(lvlf, 2.0f), 5.0f) - 2.0f;
    const int l = (int)lvlf;

    int sz; size_t lvl_off;
    if      (l == 0) { sz = 200; lvl_off = WS_OFF0; }
    else if (l == 1) { sz = 100; lvl_off = WS_OFF1; }
    else if (l == 2) { sz = 50;  lvl_off = WS_OFF2; }
    else             { sz = 25;  lvl_off = WS_OFF3; }
    const int HW = sz * sz;
    const float scale = 0.25f / (float)(1 << l);

    if (t < 196) {
        const int bin = t >> 2, sub = t & 3;
        const int ph = bin / POUT, pw = bin % POUT;
        const int iy = sub >> 1,  ix = sub & 1;

        const float x0 = box.x * scale, y0 = box.y * scale;
        const float x1 = box.z * scale, y1 = box.w * scale;
        const float bin_w = fmaxf(x1 - x0, 1.0f) / (float)POUT;
        const float bin_h = fmaxf(y1 - y0, 1.0f) / (float)POUT;

        const float ys = y0 + ((float)ph + ((float)iy + 0.5f) * 0.5f) * bin_h;
        const float xs = x0 + ((float)pw + ((float)ix + 0.5f) * 0.5f) * bin_w;

        const bool  vy  = (ys >= -1.0f) && (ys <= (float)sz);
        const float cy  = fmaxf(ys, 0.0f);
        const int   yl0 = (int)floorf(cy);
        const bool  ey  = yl0 >= sz - 1;
        const int   yl  = ey ? sz - 1 : yl0;
        const int   yh  = ey ? sz - 1 : yl0 + 1;
        const float ly  = ey ? 0.0f : cy - (float)yl0;

        const bool  vx  = (xs >= -1.0f) && (xs <= (float)sz);
        const float cx  = fmaxf(xs, 0.0f);
        const int   xl0 = (int)floorf(cx);
        const bool  ex  = xl0 >= sz - 1;
        const int   xl  = ex ? sz - 1 : xl0;
        const float lx  = ex ? 0.0f : cx - (float)xl0;

        const float hy = 1.0f - ly, hx = 1.0f - lx;
        const float m  = (vy && vx) ? 0.25f : 0.0f;   // fold subsample mean
        const float w00 = hy * hx * m, w01 = hy * lx * m;
        const float w10 = ly * hx * m, w11 = ly * lx * m;

        __half2 p01 = __floats2half2_rn(w00, w01);
        __half2 p23 = __floats2half2_rn(w10, w11);

        int4 rec;
        rec.x = (yl * sz + xl) * NCH;                 // o00 (in-bounds)
        rec.y = *reinterpret_cast<const int*>(&p01);
        rec.z = *reinterpret_cast<const int*>(&p23);
        rec.w = (yh * sz + xl) * NCH;                 // o10 (in-bounds)
        sRec[t] = rec;
    }
    __syncthreads();

    const float* fb = ws + lvl_off + (size_t)b * (size_t)HW * NCH + t;

    float acc[49];
    #pragma unroll
    for (int bin = 0; bin < 49; ++bin) {
        float a = 0.0f;
        #pragma unroll
        for (int sub = 0; sub < 4; ++sub) {
            const int4 rec = sRec[bin * 4 + sub];
            const __half2 h01 = *reinterpret_cast<const __half2*>(&rec.y);
            const __half2 h23 = *reinterpret_cast<const __half2*>(&rec.z);
            const float2 w01 = __half22float2(h01);
            const float2 w23 = __half22float2(h23);
            a += w01.x * fb[rec.x] + w01.y * fb[rec.x + NCH]
               + w23.x * fb[rec.w] + w23.y * fb[rec.w + NCH];
        }
        acc[bin] = a;
    }

    // ---- staged coalesced stores: 64 channels x 49 bins per round ----
    __syncthreads();
    float* obase = out + (size_t)n * (NCH * 49);
    #pragma unroll
    for (int r = 0; r < 4; ++r) {
        if ((t >> 6) == r) {
            #pragma unroll
            for (int i = 0; i < 49; ++i) sStage[(t & 63) * 49 + i] = acc[i];
        }
        __syncthreads();
        float4* d4 = (float4*)(obase + r * (64 * 49));
        const float4* s4 = (const float4*)sStage;
        for (int i = t; i < 64 * 49 / 4; i += 256) d4[i] = s4[i];
        __syncthreads();
    }
}

// ---------------- fallback (round-1 NCHW kernel) ----------------
__global__ __launch_bounds__(256, 4) void roi_align_nchw_kernel(
    const float* __restrict__ f0, const float* __restrict__ f1,
    const float* __restrict__ f2, const float* __restrict__ f3,
    const float* __restrict__ props, float* __restrict__ out, int boxes_per_img)
{
    const int n = blockIdx.x;
    const int t = threadIdx.x;
    if (t >= 196) return;
    const int bin = t >> 2, q = t & 3;
    const int ph = bin / POUT, pw = bin % POUT;
    const int iy = q >> 1,    ix = q & 1;
    const int b = n / boxes_per_img;

    const float4 box = ((const float4*)props)[n];
    const float area = (box.z - box.x) * (box.w - box.y);
    float lvlf = floorf(4.0f + log2f(sqrtf(area) / 224.0f + 1e-6f));
    lvlf = fminf(fmaxf(lvlf, 2.0f), 5.0f) - 2.0f;
    const int l = (int)lvlf;

    const float* feat; int sz;
    if      (l == 0) { feat = f0; sz = 200; }
    else if (l == 1) { feat = f1; sz = 100; }
    else if (l == 2) { feat = f2; sz = 50;  }
    else             { feat = f3; sz = 25;  }
    const float scale = 0.25f / (float)(1 << l);

    const float x0 = box.x * scale, y0 = box.y * scale;
    const float x1 = box.z * scale, y1 = box.w * scale;
    const float bin_w = fmaxf(x1 - x0, 1.0f) / (float)POUT;
    const float bin_h = fmaxf(y1 - y0, 1.0f) / (float)POUT;
    const float ysamp = y0 + ((float)ph + ((float)iy + 0.5f) * 0.5f) * bin_h;
    const float xsamp = x0 + ((float)pw + ((float)ix + 0.5f) * 0.5f) * bin_w;

    const bool  vy  = (ysamp >= -1.0f) && (ysamp <= (float)sz);
    const float cy  = fmaxf(ysamp, 0.0f);
    const int   yl0 = (int)floorf(cy);
    const bool  ey  = yl0 >= sz - 1;
    const int   yl  = ey ? sz - 1 : yl0;
    const int   yh  = ey ? sz - 1 : yl0 + 1;
    const float ly  = ey ? 0.0f : cy - (float)yl0;
    const bool  vx  = (xsamp >= -1.0f) && (xsamp <= (float)sz);
    const float cx  = fmaxf(xsamp, 0.0f);
    const int   xl0 = (int)floorf(cx);
    const bool  ex  = xl0 >= sz - 1;
    const int   xl  = ex ? sz - 1 : xl0;
    const int   xh  = ex ? sz - 1 : xl0 + 1;
    const float lx  = ex ? 0.0f : cx - (float)xl0;

    const float hy = 1.0f - ly, hx = 1.0f - lx;
    const float m  = (vy && vx) ? 1.0f : 0.0f;
    const float w00 = hy * hx * m, w01 = hy * lx * m;
    const float w10 = ly * hx * m, w11 = ly * lx * m;

    const int HW = sz * sz;
    const float* base = feat + (size_t)b * NCH * HW;
    int o00 = yl * sz + xl, o01 = yl * sz + xh;
    int o10 = yh * sz + xl, o11 = yh * sz + xh;
    float* op = out + (size_t)n * NCH * (POUT * POUT) + bin;

    #pragma unroll 4
    for (int cch = 0; cch < NCH; ++cch) {
        float v = w00 * base[o00] + w01 * base[o01]
                + w10 * base[o10] + w11 * base[o11];
        v += __shfl_xor(v, 1);
        v += __shfl_xor(v, 2);
        if (q == 0) op[cch * (POUT * POUT)] = v * 0.25f;
        o00 += HW; o01 += HW; o10 += HW; o11 += HW;
    }
}

extern "C" void kernel_launch(void* const* d_in, const int* in_sizes, int n_in,
                              void* d_out, int out_size, void* d_ws, size_t ws_size,
                              hipStream_t stream) {
    const float* f0 = (const float*)d_in[0];
    const float* f1 = (const float*)d_in[1];
    const float* f2 = (const float*)d_in[2];
    const float* f3 = (const float*)d_in[3];
    const float* props = (const float*)d_in[4];
    float* out = (float*)d_out;

    const int N = in_sizes[4] / 4;                 // 1024 boxes
    const int B = in_sizes[0] / (NCH * HW0);       // 2 images
    const int boxes_per_img = N / B;               // 512

    if (ws_size >= WS_NEED) {
        float* wsf = (float*)d_ws;
        transpose_cl_kernel<<<dim3((HW0 + 63) / 64, 4, B), 256, 0, stream>>>(f0, wsf + WS_OFF0, HW0);
        transpose_cl_kernel<<<dim3((HW1 + 63) / 64, 4, B), 256, 0, stream>>>(f1, wsf + WS_OFF1, HW1);
        transpose_cl_kernel<<<dim3((HW2 + 63) / 64, 4, B), 256, 0, stream>>>(f2, wsf + WS_OFF2, HW2);
        transpose_cl_kernel<<<dim3((HW3 + 63) / 64, 4, B), 256, 0, stream>>>(f3, wsf + WS_OFF3, HW3);
        roi_gather_kernel<<<N, 256, 0, stream>>>(wsf, props, out, boxes_per_img);
    } else {
        roi_align_nchw_kernel<<<N, 256, 0, stream>>>(f0, f1, f2, f3, props, out, boxes_per_img);
    }
}